// Round 6
// baseline (281.377 us; speedup 1.0000x reference)
//
#include <hip/hip_runtime.h>
#include <math.h>

#define B_   32
#define N_   128
#define H_   100
#define ROWS (B_ * N_)    // 4096
#define RH   (ROWS * H_)  // 409600

// ---------------------------------------------------------------------------
// K1: hv = nodes@Wv, hw = nodes@Ww. 2 rows per 256-thread block; lane j = h.
__global__ __launch_bounds__(256, 6) void k_proj0(const float* __restrict__ nodes,
                                                  const float* __restrict__ Wv,
                                                  const float* __restrict__ Ww,
                                                  float* __restrict__ hv,
                                                  float* __restrict__ hw) {
    __shared__ float nod_s[2][H_];
    const int row0 = blockIdx.x * 2;
    const int t = threadIdx.x, r = t >> 7, j = t & 127;
    {
        const float4* ng = (const float4*)(nodes + (size_t)row0 * H_);
        if (t < 50) ((float4*)nod_s)[t] = ng[t];
    }
    __syncthreads();
    if (j >= H_) return;
    const float4* hr4 = (const float4*)nod_s[r];
    float va = 0.f, wa = 0.f;
#pragma unroll 5
    for (int k4 = 0; k4 < 25; ++k4) {
        const float4 h4 = hr4[k4];
        const int k = k4 * 4;
        va = fmaf(h4.x, Wv[(k + 0) * H_ + j], va);
        wa = fmaf(h4.x, Ww[(k + 0) * H_ + j], wa);
        va = fmaf(h4.y, Wv[(k + 1) * H_ + j], va);
        wa = fmaf(h4.y, Ww[(k + 1) * H_ + j], wa);
        va = fmaf(h4.z, Wv[(k + 2) * H_ + j], va);
        wa = fmaf(h4.z, Ww[(k + 2) * H_ + j], wa);
        va = fmaf(h4.w, Wv[(k + 3) * H_ + j], va);
        wa = fmaf(h4.w, Ww[(k + 3) * H_ + j], wa);
    }
    hv[(size_t)(row0 + r) * H_ + j] = va;
    hw[(size_t)(row0 + r) * H_ + j] = wa;
}

// ---------------------------------------------------------------------------
// K2: one fused message pass. 2 rows per 256-thread block (r=t>>7, j=t&127).
// Message loop: e broadcast from global (L1-hot), mask recomputed in VALU,
// hw coalesced from global; zero LDS in the loop. node-mask accumulated
// in-register. Then tanh update; mode 1 -> next-pass hv/hw projections;
// mode 2 -> fused readout (relu([nh,nodes]@Wr) masked block-reduce + atomic).
__global__ __launch_bounds__(256, 6) void k_pass(const float* __restrict__ edges,
                                                 const float* __restrict__ We,
                                                 const float* __restrict__ Wu,
                                                 const float* __restrict__ Wv,
                                                 const float* __restrict__ Ww,
                                                 const float* __restrict__ Wr,
                                                 const float* __restrict__ nodes,
                                                 float* __restrict__ hv_io,
                                                 const float* __restrict__ hw_in,
                                                 float* __restrict__ hw_out,
                                                 const float* __restrict__ hid_in,
                                                 float* __restrict__ hidden,
                                                 float* __restrict__ out,
                                                 int mode) {
    __shared__ float hid_s[2][H_];    // pre-update hidden rows
    __shared__ float msg_s[2][H_];
    __shared__ float hn_s[2][H_];     // post-update hidden rows
    __shared__ float nod_s[2][H_];    // readout only
    __shared__ float red_s[2][H_];    // readout only

    const int row0 = blockIdx.x * 2;
    const int b = row0 >> 7;
    const int t = threadIdx.x, r = t >> 7, j = t & 127;
    const int row = row0 + r;
    const bool act = (j < H_);

    {   // stage pre-update hidden rows (50 float4); nodes too if readout pass
        const float4* hg = (const float4*)(hid_in + (size_t)row0 * H_);
        if (t < 50) ((float4*)hid_s)[t] = hg[t];
        if (mode == 2) {
            const float4* ng = (const float4*)(nodes + (size_t)row0 * H_);
            if (t < 50) ((float4*)nod_s)[t] = ng[t];
        }
    }
    __syncthreads();

    float asum = 0.f;   // row adjacency sum (all lanes redundantly)
    if (act) {
        const float hvv = hv_io[(size_t)row * H_ + j];
        const float we0 = We[0 * H_ + j], we1 = We[1 * H_ + j];
        const float we2 = We[2 * H_ + j], we3 = We[3 * H_ + j];
        const float4* ev = (const float4*)edges + (size_t)row * N_;
        const float* hwp = hw_in + (size_t)b * N_ * H_ + j;
        float acc = 0.f;
#pragma unroll 8
        for (int w = 0; w < N_; ++w) {
            const float4 e = ev[w];               // lane-broadcast, L1-hot
            const float  hww = hwp[w * H_];       // coalesced 256B/wave
            const float  s = (e.x + e.y) + (e.z + e.w);
            const float  m = (s != 0.f) ? 1.f : 0.f;
            asum += s;
            float p = hvv + hww;
            p = fmaf(e.x, we0, p);
            p = fmaf(e.y, we1, p);
            p = fmaf(e.z, we2, p);
            p = fmaf(e.w, we3, p);
            acc = fmaf(m, fmaxf(p, 0.f), acc);
        }
        msg_s[r][j] = acc;
    }
    __syncthreads();

    const float nm = (asum != 0.f) ? 1.f : 0.f;
    if (act) {
        const float4* hr4 = (const float4*)hid_s[r];
        const float4* mr4 = (const float4*)msg_s[r];
        float u = 0.f;
#pragma unroll 4
        for (int k4 = 0; k4 < 25; ++k4) {
            const float4 h4 = hr4[k4];
            const int k = k4 * 4;
            u = fmaf(h4.x, Wu[(k + 0) * H_ + j], u);
            u = fmaf(h4.y, Wu[(k + 1) * H_ + j], u);
            u = fmaf(h4.z, Wu[(k + 2) * H_ + j], u);
            u = fmaf(h4.w, Wu[(k + 3) * H_ + j], u);
        }
#pragma unroll 4
        for (int k4 = 0; k4 < 25; ++k4) {
            const float4 m4 = mr4[k4];
            const int k = H_ + k4 * 4;
            u = fmaf(m4.x, Wu[(k + 0) * H_ + j], u);
            u = fmaf(m4.y, Wu[(k + 1) * H_ + j], u);
            u = fmaf(m4.z, Wu[(k + 2) * H_ + j], u);
            u = fmaf(m4.w, Wu[(k + 3) * H_ + j], u);
        }
        const float nh = (nm != 0.f) ? tanhf(u) : hid_s[r][j];
        hn_s[r][j] = nh;
        if (mode == 1) hidden[(size_t)row * H_ + j] = nh;
    }

    if (mode == 1) {        // next pass's hv/hw from fresh hidden (own rows)
        __syncthreads();
        if (act) {
            const float4* hr4 = (const float4*)hn_s[r];
            float va = 0.f, wa = 0.f;
#pragma unroll 5
            for (int k4 = 0; k4 < 25; ++k4) {
                const float4 h4 = hr4[k4];
                const int k = k4 * 4;
                va = fmaf(h4.x, Wv[(k + 0) * H_ + j], va);
                wa = fmaf(h4.x, Ww[(k + 0) * H_ + j], wa);
                va = fmaf(h4.y, Wv[(k + 1) * H_ + j], va);
                wa = fmaf(h4.y, Ww[(k + 1) * H_ + j], wa);
                va = fmaf(h4.z, Wv[(k + 2) * H_ + j], va);
                wa = fmaf(h4.z, Ww[(k + 2) * H_ + j], wa);
                va = fmaf(h4.w, Wv[(k + 3) * H_ + j], va);
                wa = fmaf(h4.w, Ww[(k + 3) * H_ + j], wa);
            }
            hv_io[(size_t)row * H_ + j] = va;     // row-local: safe in-place
            hw_out[(size_t)row * H_ + j] = wa;    // double-buffered
        }
    } else {                // mode 2: fused readout
        __syncthreads();
        if (act) {
            const float4* hr4 = (const float4*)hn_s[r];
            const float4* nr4 = (const float4*)nod_s[r];
            float u = 0.f;
#pragma unroll 4
            for (int k4 = 0; k4 < 25; ++k4) {
                const float4 h4 = hr4[k4];
                const int k = k4 * 4;
                u = fmaf(h4.x, Wr[(k + 0) * H_ + j], u);
                u = fmaf(h4.y, Wr[(k + 1) * H_ + j], u);
                u = fmaf(h4.z, Wr[(k + 2) * H_ + j], u);
                u = fmaf(h4.w, Wr[(k + 3) * H_ + j], u);
            }
#pragma unroll 4
            for (int k4 = 0; k4 < 25; ++k4) {
                const float4 n4 = nr4[k4];
                const int k = H_ + k4 * 4;
                u = fmaf(n4.x, Wr[(k + 0) * H_ + j], u);
                u = fmaf(n4.y, Wr[(k + 1) * H_ + j], u);
                u = fmaf(n4.z, Wr[(k + 2) * H_ + j], u);
                u = fmaf(n4.w, Wr[(k + 3) * H_ + j], u);
            }
            red_s[r][j] = nm * fmaxf(u, 0.f);
        }
        __syncthreads();
        if (t < H_) atomicAdd(out + b * H_ + t, red_s[0][t] + red_s[1][t]);
    }
}

// ---------------------------------------------------------------------------
extern "C" void kernel_launch(void* const* d_in, const int* in_sizes, int n_in,
                              void* d_out, int out_size, void* d_ws, size_t ws_size,
                              hipStream_t stream) {
    const float* nodes = (const float*)d_in[0];
    const float* edges = (const float*)d_in[1];
    const float* Wv    = (const float*)d_in[2];
    const float* Ww    = (const float*)d_in[3];
    const float* We    = (const float*)d_in[4];
    const float* Wu    = (const float*)d_in[5];
    const float* Wr    = (const float*)d_in[6];
    float* out = (float*)d_out;

    float* hidden = (float*)d_ws;     // RH
    float* hv     = hidden + RH;      // RH
    float* hwA    = hv + RH;          // RH
    float* hwB    = hwA + RH;         // RH

    hipMemsetAsync(d_out, 0, (size_t)out_size * sizeof(float), stream);

    k_proj0<<<ROWS / 2, 256, 0, stream>>>(nodes, Wv, Ww, hv, hwA);

    k_pass<<<ROWS / 2, 256, 0, stream>>>(edges, We, Wu, Wv, Ww, Wr, nodes,
                                         hv, hwA, hwB, nodes, hidden, out, 1);
    k_pass<<<ROWS / 2, 256, 0, stream>>>(edges, We, Wu, Wv, Ww, Wr, nodes,
                                         hv, hwB, hwA, hidden, hidden, out, 1);
    k_pass<<<ROWS / 2, 256, 0, stream>>>(edges, We, Wu, Wv, Ww, Wr, nodes,
                                         hv, hwA, hwB, hidden, hidden, out, 2);
}